// Round 2
// baseline (10282.009 us; speedup 1.0000x reference)
//
#include <hip/hip_runtime.h>

#define LAYERS 8
#define SEQ 256
#define BATCH 64
#define HID 512
#define G4 2048   // 4*HID, pytorch gate order i,f,g,o
#define NSENS 64
#define DEPTH 4   // h ring depth (power of 2)

typedef _Float16 h16;
typedef h16 h16x8 __attribute__((ext_vector_type(8)));
typedef float f32x4 __attribute__((ext_vector_type(4)));

// ---- workspace layout (bytes) ----
#define WHH_ELEMS   (LAYERS * G4 * HID)
#define WIHR_ELEMS  ((LAYERS - 1) * G4 * HID)
#define WIH0_ELEMS  (G4 * NSENS)
#define WF16_BYTES  ((size_t)(WHH_ELEMS + WIHR_ELEMS + WIH0_ELEMS) * 2)   // 31,719,424
#define BIASC_OFF   (WF16_BYTES)                                          // fp32 [L][G4]
#define XT_OFF      (BIASC_OFF + (size_t)LAYERS * G4 * 4)                 // h16 [T][B][NSENS]
#define HRING_OFF   (XT_OFF + (size_t)SEQ * BATCH * NSENS * 2)            // h16 [L][DEPTH][B][H]
#define H7_OFF      (HRING_OFF + (size_t)LAYERS * DEPTH * BATCH * HID * 2)// fp32 [B][H]
#define READY_OFF   (H7_OFF + (size_t)BATCH * HID * 4)                    // u32 [L][SEQ][16] (64B spaced)
#define DONE_OFF    (READY_OFF + (size_t)LAYERS * SEQ * 16 * 4)           // u32 [L][SEQ][16]
// end = DONE_OFF + L*SEQ*16*4 = 36,372,480 bytes

__device__ __forceinline__ unsigned aload(const unsigned* p) {
  return __hip_atomic_load(p, __ATOMIC_RELAXED, __HIP_MEMORY_SCOPE_AGENT);
}
__device__ __forceinline__ float fast_sig(float x) {
  return 1.f / (1.f + __expf(-x));
}
__device__ __forceinline__ float fast_tanh(float x) {
  x = fminf(fmaxf(x, -10.f), 10.f);
  float e2 = __expf(2.f * x);
  return (e2 - 1.f) / (e2 + 1.f);
}

// ---------------- prep: fp16 weights, combined bias, x transpose, zero state+flags ----------------
__global__ void prep_kernel(const float* __restrict__ x,
                            const float* __restrict__ Wih0,
                            const float* __restrict__ WihR,
                            const float* __restrict__ Whh,
                            const float* __restrict__ bih,
                            const float* __restrict__ bhh,
                            h16* __restrict__ wf16,
                            float* __restrict__ biasc,
                            h16* __restrict__ xT,
                            h16* __restrict__ hring,
                            unsigned* __restrict__ ready,
                            unsigned* __restrict__ done) {
  const int tid = blockIdx.x * blockDim.x + threadIdx.x;
  const int nt = gridDim.x * blockDim.x;
  for (int i = tid; i < WHH_ELEMS; i += nt) wf16[i] = (h16)Whh[i];
  for (int i = tid; i < WIHR_ELEMS; i += nt) wf16[WHH_ELEMS + i] = (h16)WihR[i];
  for (int i = tid; i < WIH0_ELEMS; i += nt) wf16[WHH_ELEMS + WIHR_ELEMS + i] = (h16)Wih0[i];
  for (int i = tid; i < LAYERS * G4; i += nt) biasc[i] = bih[i] + bhh[i];
  for (int i = tid; i < SEQ * BATCH * NSENS; i += nt) {
    int t = i / (BATCH * NSENS);
    int r = i - t * (BATCH * NSENS);
    int b = r / NSENS;
    int s2 = r - b * NSENS;
    xT[i] = (h16)x[(b * SEQ + t) * NSENS + s2];
  }
  for (int i = tid; i < LAYERS * DEPTH * BATCH * HID; i += nt) hring[i] = (h16)0.f;
  for (int i = tid; i < LAYERS * SEQ * 16; i += nt) { ready[i] = 0u; done[i] = 0u; }
}

// ---------------- persistent dataflow LSTM ----------------
// blockIdx: layer = blockIdx & 7 (XCD affinity), slice = blockIdx >> 3 (16 hidden units).
// wave kw = K-chunk (128 of 512). Weights for this WG's 64 gate rows live in VGPRs.
// Each step: all 4 waves compute 64x64 partial gates over their K-chunk; reduce via LDS;
// epilogue applies LSTM cell (c in registers); h goes to global ring with flag handshake.
__global__ __launch_bounds__(256, 2) void lstm_persist(
    const h16* __restrict__ wf16, const float* __restrict__ biasc,
    const h16* __restrict__ xT, h16* __restrict__ hring,
    float* __restrict__ h7, unsigned* __restrict__ ready,
    unsigned* __restrict__ done) {
  const int l = blockIdx.x & 7;
  const int slice = blockIdx.x >> 3;
  const int tid = threadIdx.x;
  const int kw = tid >> 6;     // wave = K-chunk index
  const int lane = tid & 63;
  const int nlo = lane & 15;
  const int quad = lane >> 4;

  __shared__ float pbuf[4 * 64 * 64];  // [wave][n(64)][m(64)] fp32, 16B-chunk XOR swizzled

  const h16* Whh = wf16 + (size_t)l * G4 * HID;
  const h16* Wih = (l == 0) ? (wf16 + WHH_ELEMS + WIHR_ELEMS)
                            : (wf16 + WHH_ELEMS + (size_t)(l - 1) * G4 * HID);

  // ---- load persistent weight fragments into registers ----
  h16x8 bhh[16];   // [g*4+ks]
  h16x8 bihf[16];
  {
    const int row_in_gate = slice * 16 + nlo;
#pragma unroll
    for (int g = 0; g < 4; ++g) {
      const size_t rhh = (size_t)(g * HID + row_in_gate) * HID + kw * 128 + quad * 8;
#pragma unroll
      for (int ks = 0; ks < 4; ++ks)
        bhh[g * 4 + ks] = *(const h16x8*)(Whh + rhh + ks * 32);
      if (l == 0) {
        if (kw < 2)
          bihf[g * 4] = *(const h16x8*)(Wih + (size_t)(g * HID + row_in_gate) * NSENS + kw * 32 + quad * 8);
      } else {
        const size_t rih = (size_t)(g * HID + row_in_gate) * HID + kw * 128 + quad * 8;
#pragma unroll
        for (int ks = 0; ks < 4; ++ks)
          bihf[g * 4 + ks] = *(const h16x8*)(Wih + rih + ks * 32);
      }
    }
  }

  // ---- epilogue thread mapping: j = hidden-within-slice, 4 batches per thread ----
  const int j = tid & 15;
  const int bg = tid >> 4;           // 0..15, batches bg*4..bg*4+3
  const int jj = slice * 16 + j;
  float biasr[4];
#pragma unroll
  for (int g = 0; g < 4; ++g) biasr[g] = biasc[l * G4 + g * HID + jj];
  float cr[4] = {0.f, 0.f, 0.f, 0.f};

  unsigned* rdy_l = ready + (size_t)l * SEQ * 16;
  unsigned* rdy_lm1 = ready + (size_t)(l > 0 ? l - 1 : 0) * SEQ * 16;
  unsigned* dn_l = done + (size_t)l * SEQ * 16;
  unsigned* dn_lm1 = done + (size_t)(l > 0 ? l - 1 : 0) * SEQ * 16;

#pragma clang loop unroll(disable)
  for (int t = 0; t < SEQ; ++t) {
    const int slot_r = (t + DEPTH - 1) & (DEPTH - 1);
    const int slot_w = t & (DEPTH - 1);

    // ---- wait for inputs ----
    if (tid == 0) {
      if (t > 0) while (aload(rdy_l + (t - 1) * 16) < 32u) {}
      if (l > 0) while (aload(rdy_lm1 + t * 16) < 32u) {}
    }
    __syncthreads();
    __threadfence();  // acquire: invalidate stale cached h

    const h16* hprev = hring + ((size_t)l * DEPTH + slot_r) * BATCH * HID;

    f32x4 acc[16];
#pragma unroll
    for (int i = 0; i < 16; ++i) acc[i] = (f32x4){0.f, 0.f, 0.f, 0.f};

    // ---- recurrent GEMM over this wave's K-chunk ----
#pragma unroll
    for (int ks = 0; ks < 4; ++ks) {
      h16x8 a[4];
#pragma unroll
      for (int mt = 0; mt < 4; ++mt)
        a[mt] = *(const h16x8*)(hprev + (size_t)(mt * 16 + nlo) * HID + kw * 128 + ks * 32 + quad * 8);
#pragma unroll
      for (int g = 0; g < 4; ++g)
#pragma unroll
        for (int mt = 0; mt < 4; ++mt)
          acc[g * 4 + mt] = __builtin_amdgcn_mfma_f32_16x16x32_f16(a[mt], bhh[g * 4 + ks], acc[g * 4 + mt], 0, 0, 0);
    }
    // ---- input-projection GEMM ----
    if (l == 0) {
      if (kw < 2) {
        const h16* xrow = xT + (size_t)t * BATCH * NSENS;
        h16x8 a[4];
#pragma unroll
        for (int mt = 0; mt < 4; ++mt)
          a[mt] = *(const h16x8*)(xrow + (size_t)(mt * 16 + nlo) * NSENS + kw * 32 + quad * 8);
#pragma unroll
        for (int g = 0; g < 4; ++g)
#pragma unroll
          for (int mt = 0; mt < 4; ++mt)
            acc[g * 4 + mt] = __builtin_amdgcn_mfma_f32_16x16x32_f16(a[mt], bihf[g * 4], acc[g * 4 + mt], 0, 0, 0);
      }
    } else {
      const h16* hlow = hring + ((size_t)(l - 1) * DEPTH + slot_w) * BATCH * HID;
#pragma unroll
      for (int ks = 0; ks < 4; ++ks) {
        h16x8 a[4];
#pragma unroll
        for (int mt = 0; mt < 4; ++mt)
          a[mt] = *(const h16x8*)(hlow + (size_t)(mt * 16 + nlo) * HID + kw * 128 + ks * 32 + quad * 8);
#pragma unroll
        for (int g = 0; g < 4; ++g)
#pragma unroll
          for (int mt = 0; mt < 4; ++mt)
            acc[g * 4 + mt] = __builtin_amdgcn_mfma_f32_16x16x32_f16(a[mt], bihf[g * 4 + ks], acc[g * 4 + mt], 0, 0, 0);
      }
    }

    // ---- partials -> LDS (C/D layout: m = quad*4+reg+16*mt, n = nlo; chunk-XOR swizzle) ----
#pragma unroll
    for (int g = 0; g < 4; ++g)
#pragma unroll
      for (int mt = 0; mt < 4; ++mt) {
        int idx = ((kw << 6) + (g << 4) + nlo) * 64 + ((((mt << 2) + quad) ^ (nlo & 7)) << 2);
        *(f32x4*)(pbuf + idx) = acc[g * 4 + mt];
      }
    __syncthreads();  // all MFMAs done => all h_low reads consumed

    if (tid == 0 && l > 0) atomicAdd(dn_lm1 + t * 16, 1u);

    // ---- epilogue: reduce 4 wave-partials, LSTM cell, c in regs ----
    float hv[4];
    {
      float gv[4][4];
#pragma unroll
      for (int g = 0; g < 4; ++g) {
        int base = ((g << 4) + j) * 64 + ((bg ^ (j & 7)) << 2);
        f32x4 s = *(const f32x4*)(pbuf + base);
#pragma unroll
        for (int w = 1; w < 4; ++w)
          s += *(const f32x4*)(pbuf + (w << 12) + base);
#pragma unroll
        for (int i = 0; i < 4; ++i) gv[g][i] = s[i] + biasr[g];
      }
#pragma unroll
      for (int i = 0; i < 4; ++i) {
        float iv = fast_sig(gv[0][i]);
        float fv = fast_sig(gv[1][i]);
        float gg = fast_tanh(gv[2][i]);
        float ov = fast_sig(gv[3][i]);
        float cn = fv * cr[i] + iv * gg;
        cr[i] = cn;
        hv[i] = ov * fast_tanh(cn);
      }
    }

    // ---- backpressure: slot we write holds t-DEPTH; its readers must be done ----
    if (tid == 0 && l < LAYERS - 1 && t >= DEPTH) {
      while (aload(dn_l + (t - DEPTH) * 16) < 32u) {}
    }
    __syncthreads();

    h16* hout = hring + ((size_t)l * DEPTH + slot_w) * BATCH * HID;
#pragma unroll
    for (int i = 0; i < 4; ++i) {
      h16 hval = (h16)hv[i];
      unsigned short bits = __builtin_bit_cast(unsigned short, hval);
      __hip_atomic_store((unsigned short*)(hout + (size_t)(bg * 4 + i) * HID + jj), bits,
                         __ATOMIC_RELAXED, __HIP_MEMORY_SCOPE_AGENT);
      if (l == LAYERS - 1 && t == SEQ - 1) h7[(size_t)(bg * 4 + i) * HID + jj] = hv[i];
    }
    __threadfence();   // release: drain stores
    __syncthreads();
    if (tid == 0) atomicAdd(rdy_l + t * 16, 1u);
  }
}

// ---------------- head: out = h7 @ Wlin^T + blin ----------------
__global__ void final_kernel(const float* __restrict__ h7,
                             const float* __restrict__ Wlin,
                             const float* __restrict__ blin,
                             float* __restrict__ out) {
  int tid = threadIdx.x;
  if (tid < BATCH * 2) {
    int b = tid >> 1;
    int o = tid & 1;
    float s = 0.f;
    for (int jx = 0; jx < HID; ++jx) s += h7[(size_t)b * HID + jx] * Wlin[o * HID + jx];
    out[b * 2 + o] = s + blin[o];
  }
}

extern "C" void kernel_launch(void* const* d_in, const int* in_sizes, int n_in,
                              void* d_out, int out_size, void* d_ws, size_t ws_size,
                              hipStream_t stream) {
  (void)in_sizes; (void)n_in; (void)out_size; (void)ws_size;
  const float* x    = (const float*)d_in[0];
  const float* Wih0 = (const float*)d_in[1];
  const float* WihR = (const float*)d_in[2];
  const float* Whh  = (const float*)d_in[3];
  const float* bih  = (const float*)d_in[4];
  const float* bhh  = (const float*)d_in[5];
  const float* Wlin = (const float*)d_in[6];
  const float* blin = (const float*)d_in[7];
  float* out = (float*)d_out;

  char* ws = (char*)d_ws;
  h16* wf16       = (h16*)(ws);
  float* biasc    = (float*)(ws + BIASC_OFF);
  h16* xT         = (h16*)(ws + XT_OFF);
  h16* hring      = (h16*)(ws + HRING_OFF);
  float* h7       = (float*)(ws + H7_OFF);
  unsigned* ready = (unsigned*)(ws + READY_OFF);
  unsigned* done  = (unsigned*)(ws + DONE_OFF);

  prep_kernel<<<512, 256, 0, stream>>>(x, Wih0, WihR, Whh, bih, bhh,
                                       wf16, biasc, xT, hring, ready, done);
  lstm_persist<<<256, 256, 0, stream>>>(wf16, biasc, xT, hring, h7, ready, done);
  final_kernel<<<1, 128, 0, stream>>>(h7, Wlin, blin, out);
}

// Round 3
// 4646.782 us; speedup vs baseline: 2.2127x; 2.2127x over previous
//
#include <hip/hip_runtime.h>

#define LAYERS 8
#define SEQ 256
#define BATCH 64
#define HID 512
#define G4 2048   // 4*HID, pytorch gate order i,f,g,o
#define NSENS 64
#define DEPTH 4   // h ring depth (power of 2)

typedef _Float16 h16;
typedef h16 h16x8 __attribute__((ext_vector_type(8)));
typedef float f32x4 __attribute__((ext_vector_type(4)));

// ---- workspace layout (bytes) ----
#define WHH_ELEMS   (LAYERS * G4 * HID)
#define WIHR_ELEMS  ((LAYERS - 1) * G4 * HID)
#define WIH0_ELEMS  (G4 * NSENS)
#define WF16_BYTES  ((size_t)(WHH_ELEMS + WIHR_ELEMS + WIH0_ELEMS) * 2)   // 31,719,424
#define BIASC_OFF   (WF16_BYTES)                                          // fp32 [L][G4]
#define XT_OFF      (BIASC_OFF + (size_t)LAYERS * G4 * 4)                 // h16 [T][B][NSENS]
#define HRING_OFF   (XT_OFF + (size_t)SEQ * BATCH * NSENS * 2)            // h16 [L][DEPTH][B][H]
#define H7_OFF      (HRING_OFF + (size_t)LAYERS * DEPTH * BATCH * HID * 2)// fp32 [B][H]
#define READY_OFF   (H7_OFF + (size_t)BATCH * HID * 4)                    // u32 [L][32] progress
#define DONE_OFF    (READY_OFF + (size_t)LAYERS * 32 * 4)                 // u32 [L][32] consumer progress
// end ~= 36.1 MB (< 36.37 MB proven available)

__device__ __forceinline__ unsigned aload(const unsigned* p) {
  return __hip_atomic_load(p, __ATOMIC_RELAXED, __HIP_MEMORY_SCOPE_AGENT);
}
__device__ __forceinline__ void astore(unsigned* p, unsigned v) {
  __hip_atomic_store(p, v, __ATOMIC_RELAXED, __HIP_MEMORY_SCOPE_AGENT);
}
// 16B fragment as two 8B device-scope relaxed atomic loads (bypass stale L1/L2)
__device__ __forceinline__ h16x8 load8_dev(const h16* p) {
  union { unsigned long long u[2]; h16x8 v; } r;
  r.u[0] = __hip_atomic_load((const unsigned long long*)p, __ATOMIC_RELAXED, __HIP_MEMORY_SCOPE_AGENT);
  r.u[1] = __hip_atomic_load((const unsigned long long*)(p + 4), __ATOMIC_RELAXED, __HIP_MEMORY_SCOPE_AGENT);
  return r.v;
}
__device__ __forceinline__ float fast_sig(float x) { return 1.f / (1.f + __expf(-x)); }
__device__ __forceinline__ float fast_tanh(float x) {
  x = fminf(fmaxf(x, -10.f), 10.f);
  float e2 = __expf(2.f * x);
  return (e2 - 1.f) / (e2 + 1.f);
}

// ---------------- prep ----------------
__global__ void prep_kernel(const float* __restrict__ x,
                            const float* __restrict__ Wih0,
                            const float* __restrict__ WihR,
                            const float* __restrict__ Whh,
                            const float* __restrict__ bih,
                            const float* __restrict__ bhh,
                            h16* __restrict__ wf16,
                            float* __restrict__ biasc,
                            h16* __restrict__ xT,
                            h16* __restrict__ hring,
                            unsigned* __restrict__ ready,
                            unsigned* __restrict__ done) {
  const int tid = blockIdx.x * blockDim.x + threadIdx.x;
  const int nt = gridDim.x * blockDim.x;
  for (int i = tid; i < WHH_ELEMS; i += nt) wf16[i] = (h16)Whh[i];
  for (int i = tid; i < WIHR_ELEMS; i += nt) wf16[WHH_ELEMS + i] = (h16)WihR[i];
  for (int i = tid; i < WIH0_ELEMS; i += nt) wf16[WHH_ELEMS + WIHR_ELEMS + i] = (h16)Wih0[i];
  for (int i = tid; i < LAYERS * G4; i += nt) biasc[i] = bih[i] + bhh[i];
  for (int i = tid; i < SEQ * BATCH * NSENS; i += nt) {
    int t = i / (BATCH * NSENS);
    int r = i - t * (BATCH * NSENS);
    int b = r / NSENS;
    int s2 = r - b * NSENS;
    xT[i] = (h16)x[(b * SEQ + t) * NSENS + s2];
  }
  for (int i = tid; i < LAYERS * DEPTH * BATCH * HID; i += nt) hring[i] = (h16)0.f;
  for (int i = tid; i < LAYERS * 32; i += nt) { ready[i] = 0u; done[i] = 0u; }
}

// ---------------- persistent dataflow LSTM ----------------
// blockIdx: layer = blockIdx & 7, slice = blockIdx >> 3 (16 hidden units).
// wave kw = K-chunk of 128. Weights in VGPRs. Per-WG progress flags; all
// cross-WG data moves via device-scope relaxed atomics (coherence point).
__global__ __launch_bounds__(256, 2) void lstm_persist(
    const h16* __restrict__ wf16, const float* __restrict__ biasc,
    const h16* __restrict__ xT, h16* __restrict__ hring,
    float* __restrict__ h7, unsigned* __restrict__ ready,
    unsigned* __restrict__ done) {
  const int l = blockIdx.x & 7;
  const int slice = blockIdx.x >> 3;
  const int tid = threadIdx.x;
  const int kw = tid >> 6;     // wave = K-chunk index
  const int lane = tid & 63;
  const int nlo = lane & 15;
  const int quad = lane >> 4;

  __shared__ float pbuf[4 * 64 * 64];  // [wave][n(64)][m(64)], 16B-chunk XOR swizzle

  const h16* Whh = wf16 + (size_t)l * G4 * HID;
  const h16* Wih = (l == 0) ? (wf16 + WHH_ELEMS + WIHR_ELEMS)
                            : (wf16 + WHH_ELEMS + (size_t)(l - 1) * G4 * HID);

  // ---- persistent weight fragments ----
  h16x8 bhh[16];   // [g*4+ks]
  h16x8 bihf[16];
  {
    const int row_in_gate = slice * 16 + nlo;
#pragma unroll
    for (int g = 0; g < 4; ++g) {
      const size_t rhh = (size_t)(g * HID + row_in_gate) * HID + kw * 128 + quad * 8;
#pragma unroll
      for (int ks = 0; ks < 4; ++ks)
        bhh[g * 4 + ks] = *(const h16x8*)(Whh + rhh + ks * 32);
      if (l == 0) {
        if (kw < 2)
          bihf[g * 4] = *(const h16x8*)(Wih + (size_t)(g * HID + row_in_gate) * NSENS + kw * 32 + quad * 8);
      } else {
        const size_t rih = (size_t)(g * HID + row_in_gate) * HID + kw * 128 + quad * 8;
#pragma unroll
        for (int ks = 0; ks < 4; ++ks)
          bihf[g * 4 + ks] = *(const h16x8*)(Wih + rih + ks * 32);
      }
    }
  }

  // ---- epilogue mapping: thread = (batch, j-quad): one 8B h store ----
  const int eb = tid >> 2;          // batch 0..63
  const int ejq = tid & 3;          // j-quad within slice
  const int jbase = slice * 16 + ejq * 4;
  float bias2[4][4];
#pragma unroll
  for (int g = 0; g < 4; ++g)
#pragma unroll
    for (int jj = 0; jj < 4; ++jj)
      bias2[g][jj] = biasc[l * G4 + g * HID + jbase + jj];
  float cr[4] = {0.f, 0.f, 0.f, 0.f};

  unsigned* rdy_own = ready + l * 32;
  unsigned* rdy_low = ready + (l > 0 ? (l - 1) * 32 : 0);
  unsigned* dn_own = done + l * 32;       // set by layer l+1's WGs
  unsigned* dn_low = done + (l > 0 ? (l - 1) * 32 : 0);

#pragma clang loop unroll(disable)
  for (int t = 0; t < SEQ; ++t) {
    const int slot_r = (t + DEPTH - 1) & (DEPTH - 1);
    const int slot_w = t & (DEPTH - 1);

    // ---- combined wait (wave 0, contention-free per-WG flags) ----
    if (tid < 64) {
      const unsigned* p1 = nullptr; unsigned tg1 = 0;
      const unsigned* p2 = nullptr; unsigned tg2 = 0;
      if (tid < 32) {
        p1 = rdy_own + tid; tg1 = (unsigned)t;                  // peers finished t-1
        if (l < LAYERS - 1) {                                   // ring backpressure
          p2 = dn_own + tid;
          tg2 = (t >= DEPTH - 1) ? (unsigned)(t - (DEPTH - 1)) : 0u;
        }
      } else if (l > 0) {
        p1 = rdy_low + (tid - 32); tg1 = (unsigned)(t + 1);     // h_low(t) available
      }
      for (;;) {
        int ok = 1;
        if (p1) ok &= (aload(p1) >= tg1) ? 1 : 0;
        if (p2) ok &= (aload(p2) >= tg2) ? 1 : 0;
        if (__all(ok)) break;
      }
    }
    __syncthreads();

    const h16* hprev = hring + ((size_t)l * DEPTH + slot_r) * BATCH * HID;

    f32x4 acc[16];
#pragma unroll
    for (int i = 0; i < 16; ++i) acc[i] = (f32x4){0.f, 0.f, 0.f, 0.f};

    // ---- recurrent GEMM over this wave's K-chunk ----
#pragma unroll
    for (int ks = 0; ks < 4; ++ks) {
      h16x8 a[4];
#pragma unroll
      for (int mt = 0; mt < 4; ++mt)
        a[mt] = load8_dev(hprev + (size_t)(mt * 16 + nlo) * HID + kw * 128 + ks * 32 + quad * 8);
#pragma unroll
      for (int g = 0; g < 4; ++g)
#pragma unroll
        for (int mt = 0; mt < 4; ++mt)
          acc[g * 4 + mt] = __builtin_amdgcn_mfma_f32_16x16x32_f16(a[mt], bhh[g * 4 + ks], acc[g * 4 + mt], 0, 0, 0);
    }
    // ---- input-projection GEMM ----
    if (l == 0) {
      if (kw < 2) {
        const h16* xrow = xT + (size_t)t * BATCH * NSENS;
        h16x8 a[4];
#pragma unroll
        for (int mt = 0; mt < 4; ++mt)
          a[mt] = *(const h16x8*)(xrow + (size_t)(mt * 16 + nlo) * NSENS + kw * 32 + quad * 8);
#pragma unroll
        for (int g = 0; g < 4; ++g)
#pragma unroll
          for (int mt = 0; mt < 4; ++mt)
            acc[g * 4 + mt] = __builtin_amdgcn_mfma_f32_16x16x32_f16(a[mt], bihf[g * 4], acc[g * 4 + mt], 0, 0, 0);
      }
    } else {
      const h16* hlow = hring + ((size_t)(l - 1) * DEPTH + slot_w) * BATCH * HID;
#pragma unroll
      for (int ks = 0; ks < 4; ++ks) {
        h16x8 a[4];
#pragma unroll
        for (int mt = 0; mt < 4; ++mt)
          a[mt] = load8_dev(hlow + (size_t)(mt * 16 + nlo) * HID + kw * 128 + ks * 32 + quad * 8);
#pragma unroll
        for (int g = 0; g < 4; ++g)
#pragma unroll
          for (int mt = 0; mt < 4; ++mt)
            acc[g * 4 + mt] = __builtin_amdgcn_mfma_f32_16x16x32_f16(a[mt], bihf[g * 4 + ks], acc[g * 4 + mt], 0, 0, 0);
      }
    }

    // ---- partials -> LDS (m = quad*4+reg+16*mt, n = nlo; chunk-XOR swizzle) ----
#pragma unroll
    for (int g = 0; g < 4; ++g)
#pragma unroll
      for (int mt = 0; mt < 4; ++mt) {
        int idx = ((kw << 6) + (g << 4) + nlo) * 64 + ((((mt << 2) + quad) ^ (nlo & 7)) << 2);
        *(f32x4*)(pbuf + idx) = acc[g * 4 + mt];
      }
    __syncthreads();  // drains all waves' h loads + pbuf stores

    // safe to let producer (l-1) overwrite h_low slot
    if (tid == 0 && l > 0) astore(dn_low + slice, (unsigned)(t + 1));

    // ---- epilogue: reduce 4 wave-partials, LSTM cell ----
    float hv[4];
    {
#pragma unroll
      for (int gi = 0; gi < 1; ++gi) {}  // keep scope
      float gsum[4][4];
#pragma unroll
      for (int g = 0; g < 4; ++g)
#pragma unroll
        for (int jj = 0; jj < 4; ++jj) {
          int n = (g << 4) + ejq * 4 + jj;
          int woff = n * 64 + ((((eb >> 2) ^ (n & 7)) << 2) | (eb & 3));
          float s = pbuf[woff] + pbuf[(1 << 12) + woff] + pbuf[(2 << 12) + woff] + pbuf[(3 << 12) + woff];
          gsum[g][jj] = s + bias2[g][jj];
        }
#pragma unroll
      for (int jj = 0; jj < 4; ++jj) {
        float iv = fast_sig(gsum[0][jj]);
        float fv = fast_sig(gsum[1][jj]);
        float gg = fast_tanh(gsum[2][jj]);
        float ov = fast_sig(gsum[3][jj]);
        float cn = fv * cr[jj] + iv * gg;
        cr[jj] = cn;
        hv[jj] = ov * fast_tanh(cn);
      }
    }

    // ---- one coalesced 8B device-scope store per thread ----
    h16* hout = hring + ((size_t)l * DEPTH + slot_w) * BATCH * HID;
    {
      union { h16 h[4]; unsigned long long u; } pk;
#pragma unroll
      for (int jj = 0; jj < 4; ++jj) pk.h[jj] = (h16)hv[jj];
      __hip_atomic_store((unsigned long long*)(hout + (size_t)eb * HID + jbase), pk.u,
                         __ATOMIC_RELAXED, __HIP_MEMORY_SCOPE_AGENT);
      if (l == LAYERS - 1 && t == SEQ - 1) {
#pragma unroll
        for (int jj = 0; jj < 4; ++jj) h7[(size_t)eb * HID + jbase + jj] = hv[jj];
      }
    }
    __syncthreads();  // drains all waves' h stores (vmcnt(0) before s_barrier)
    if (tid == 0) astore(rdy_own + slice, (unsigned)(t + 1));
  }
}

// ---------------- head ----------------
__global__ void final_kernel(const float* __restrict__ h7,
                             const float* __restrict__ Wlin,
                             const float* __restrict__ blin,
                             float* __restrict__ out) {
  int tid = threadIdx.x;
  if (tid < BATCH * 2) {
    int b = tid >> 1;
    int o = tid & 1;
    float s = 0.f;
    for (int jx = 0; jx < HID; ++jx) s += h7[(size_t)b * HID + jx] * Wlin[o * HID + jx];
    out[b * 2 + o] = s + blin[o];
  }
}

extern "C" void kernel_launch(void* const* d_in, const int* in_sizes, int n_in,
                              void* d_out, int out_size, void* d_ws, size_t ws_size,
                              hipStream_t stream) {
  (void)in_sizes; (void)n_in; (void)out_size; (void)ws_size;
  const float* x    = (const float*)d_in[0];
  const float* Wih0 = (const float*)d_in[1];
  const float* WihR = (const float*)d_in[2];
  const float* Whh  = (const float*)d_in[3];
  const float* bih  = (const float*)d_in[4];
  const float* bhh  = (const float*)d_in[5];
  const float* Wlin = (const float*)d_in[6];
  const float* blin = (const float*)d_in[7];
  float* out = (float*)d_out;

  char* ws = (char*)d_ws;
  h16* wf16       = (h16*)(ws);
  float* biasc    = (float*)(ws + BIASC_OFF);
  h16* xT         = (h16*)(ws + XT_OFF);
  h16* hring      = (h16*)(ws + HRING_OFF);
  float* h7       = (float*)(ws + H7_OFF);
  unsigned* ready = (unsigned*)(ws + READY_OFF);
  unsigned* done  = (unsigned*)(ws + DONE_OFF);

  prep_kernel<<<512, 256, 0, stream>>>(x, Wih0, WihR, Whh, bih, bhh,
                                       wf16, biasc, xT, hring, ready, done);
  lstm_persist<<<256, 256, 0, stream>>>(wf16, biasc, xT, hring, h7, ready, done);
  final_kernel<<<1, 128, 0, stream>>>(h7, Wlin, blin, out);
}

// Round 4
// 3079.837 us; speedup vs baseline: 3.3385x; 1.5088x over previous
//
#include <hip/hip_runtime.h>

#define LAYERS 8
#define SEQ 256
#define BATCH 64
#define HID 512
#define G4 2048   // 4*HID, pytorch gate order i,f,g,o
#define NSENS 64
#define DEPTH 4   // h ring depth (power of 2)

typedef _Float16 h16;
typedef h16 h16x8 __attribute__((ext_vector_type(8)));
typedef float f32x4 __attribute__((ext_vector_type(4)));

// ---- workspace layout (bytes) ----
#define WHH_ELEMS   (LAYERS * G4 * HID)
#define WIHR_ELEMS  ((LAYERS - 1) * G4 * HID)
#define WIH0_ELEMS  (G4 * NSENS)
#define WF16_BYTES  ((size_t)(WHH_ELEMS + WIHR_ELEMS + WIH0_ELEMS) * 2)   // 31,719,424
#define BIASC_OFF   (WF16_BYTES)                                          // fp32 [L][G4]
#define XT_OFF      (BIASC_OFF + (size_t)LAYERS * G4 * 4)                 // h16 [T][B][NSENS]
#define HRING_OFF   (XT_OFF + (size_t)SEQ * BATCH * NSENS * 2)            // h16 [L][DEPTH][B][H]
#define H7_OFF      (HRING_OFF + (size_t)LAYERS * DEPTH * BATCH * HID * 2)// fp32 [B][H]
#define READY_OFF   (H7_OFF + (size_t)BATCH * HID * 4)                    // u32 [L][32]
#define DONE_OFF    (READY_OFF + (size_t)LAYERS * 32 * 4)                 // u32 [L][32]
// end ~= 36.1 MB (same as R3, proven available)

__device__ __forceinline__ unsigned aload(const unsigned* p) {
  return __hip_atomic_load(p, __ATOMIC_RELAXED, __HIP_MEMORY_SCOPE_AGENT);
}
__device__ __forceinline__ void astore(unsigned* p, unsigned v) {
  __hip_atomic_store(p, v, __ATOMIC_RELAXED, __HIP_MEMORY_SCOPE_AGENT);
}
// 16B fragment as two 8B device-scope relaxed atomic loads
__device__ __forceinline__ h16x8 load8_dev(const h16* p) {
  union { unsigned long long u[2]; h16x8 v; } r;
  r.u[0] = __hip_atomic_load((const unsigned long long*)p, __ATOMIC_RELAXED, __HIP_MEMORY_SCOPE_AGENT);
  r.u[1] = __hip_atomic_load((const unsigned long long*)(p + 4), __ATOMIC_RELAXED, __HIP_MEMORY_SCOPE_AGENT);
  return r.v;
}
__device__ __forceinline__ float fast_sig(float x) { return 1.f / (1.f + __expf(-x)); }
__device__ __forceinline__ float fast_tanh(float x) {
  x = fminf(fmaxf(x, -10.f), 10.f);
  float e2 = __expf(2.f * x);
  return (e2 - 1.f) / (e2 + 1.f);
}

// ---------------- prep ----------------
__global__ void prep_kernel(const float* __restrict__ x,
                            const float* __restrict__ Wih0,
                            const float* __restrict__ WihR,
                            const float* __restrict__ Whh,
                            const float* __restrict__ bih,
                            const float* __restrict__ bhh,
                            h16* __restrict__ wf16,
                            float* __restrict__ biasc,
                            h16* __restrict__ xT,
                            h16* __restrict__ hring,
                            unsigned* __restrict__ ready,
                            unsigned* __restrict__ done) {
  const int tid = blockIdx.x * blockDim.x + threadIdx.x;
  const int nt = gridDim.x * blockDim.x;
  for (int i = tid; i < WHH_ELEMS; i += nt) wf16[i] = (h16)Whh[i];
  for (int i = tid; i < WIHR_ELEMS; i += nt) wf16[WHH_ELEMS + i] = (h16)WihR[i];
  for (int i = tid; i < WIH0_ELEMS; i += nt) wf16[WHH_ELEMS + WIHR_ELEMS + i] = (h16)Wih0[i];
  for (int i = tid; i < LAYERS * G4; i += nt) biasc[i] = bih[i] + bhh[i];
  for (int i = tid; i < SEQ * BATCH * NSENS; i += nt) {
    int t = i / (BATCH * NSENS);
    int r = i - t * (BATCH * NSENS);
    int b = r / NSENS;
    int s2 = r - b * NSENS;
    xT[i] = (h16)x[(b * SEQ + t) * NSENS + s2];
  }
  for (int i = tid; i < LAYERS * DEPTH * BATCH * HID; i += nt) hring[i] = (h16)0.f;
  for (int i = tid; i < LAYERS * 32; i += nt) { ready[i] = 0u; done[i] = 0u; }
}

// ---------------- persistent dataflow LSTM ----------------
// layer = blockIdx & 7, slice = blockIdx >> 3. wave kw = K-chunk of 128.
// Weights in VGPRs. Input-projection GEMM software-pipelined one step ahead
// (runs during peers' flag-detect latency); critical cycle = peer poll ->
// h_prev load -> Whh MFMA -> LDS reduce -> cell -> h store -> flag.
__global__ __launch_bounds__(256, 2) void lstm_persist(
    const h16* __restrict__ wf16, const float* __restrict__ biasc,
    const h16* __restrict__ xT, h16* __restrict__ hring,
    float* __restrict__ h7, unsigned* __restrict__ ready,
    unsigned* __restrict__ done) {
  const int l = blockIdx.x & 7;
  const int slice = blockIdx.x >> 3;
  const int tid = threadIdx.x;
  const int kw = tid >> 6;
  const int lane = tid & 63;
  const int nlo = lane & 15;
  const int quad = lane >> 4;

  __shared__ float pbuf[4 * 64 * 64];  // [wave][n(64)][m(64)], 16B-chunk XOR swizzle

  const h16* Whh = wf16 + (size_t)l * G4 * HID;
  const h16* Wih = (l == 0) ? (wf16 + WHH_ELEMS + WIHR_ELEMS)
                            : (wf16 + WHH_ELEMS + (size_t)(l - 1) * G4 * HID);

  // ---- persistent weight fragments ----
  h16x8 bhh[16];   // [g*4+ks]
  h16x8 bihf[16];
  {
    const int row_in_gate = slice * 16 + nlo;
#pragma unroll
    for (int g = 0; g < 4; ++g) {
      const size_t rhh = (size_t)(g * HID + row_in_gate) * HID + kw * 128 + quad * 8;
#pragma unroll
      for (int ks = 0; ks < 4; ++ks)
        bhh[g * 4 + ks] = *(const h16x8*)(Whh + rhh + ks * 32);
      if (l == 0) {
        if (kw < 2)
          bihf[g * 4] = *(const h16x8*)(Wih + (size_t)(g * HID + row_in_gate) * NSENS + kw * 32 + quad * 8);
      } else {
        const size_t rih = (size_t)(g * HID + row_in_gate) * HID + kw * 128 + quad * 8;
#pragma unroll
        for (int ks = 0; ks < 4; ++ks)
          bihf[g * 4 + ks] = *(const h16x8*)(Wih + rih + ks * 32);
      }
    }
  }

  // ---- epilogue mapping: thread = (batch, j-quad): one 8B h store ----
  const int eb = tid >> 2;
  const int ejq = tid & 3;
  const int jbase = slice * 16 + ejq * 4;
  float bias2[4][4];
#pragma unroll
  for (int g = 0; g < 4; ++g)
#pragma unroll
    for (int jj = 0; jj < 4; ++jj)
      bias2[g][jj] = biasc[l * G4 + g * HID + jbase + jj];
  float cr[4] = {0.f, 0.f, 0.f, 0.f};

  unsigned* rdy_own = ready + l * 32;
  unsigned* rdy_low = ready + (l > 0 ? (l - 1) * 32 : 0);
  unsigned* dn_own = done + l * 32;
  unsigned* dn_low = done + (l > 0 ? (l - 1) * 32 : 0);

  f32x4 acc[16];

  // ---- prefetch input contribution for timestep tp into acc ----
  auto prefetch_input = [&](int tp) {
    if (l > 0) {
      if (tid < 64) {
        int ok = (tid < 32) ? (aload(rdy_low + tid) >= (unsigned)(tp + 1)) : 1;
        while (!__all(ok)) {
          __builtin_amdgcn_s_sleep(1);
          if (tid < 32) ok = (aload(rdy_low + tid) >= (unsigned)(tp + 1)) ? 1 : 0;
        }
      }
      __syncthreads();
    }
#pragma unroll
    for (int i = 0; i < 16; ++i) acc[i] = (f32x4){0.f, 0.f, 0.f, 0.f};
    if (l == 0) {
      if (kw < 2) {
        const h16* xrow = xT + (size_t)tp * BATCH * NSENS;
        h16x8 a[4];
#pragma unroll
        for (int mt = 0; mt < 4; ++mt)
          a[mt] = *(const h16x8*)(xrow + (size_t)(mt * 16 + nlo) * NSENS + kw * 32 + quad * 8);
#pragma unroll
        for (int g = 0; g < 4; ++g)
#pragma unroll
          for (int mt = 0; mt < 4; ++mt)
            acc[g * 4 + mt] = __builtin_amdgcn_mfma_f32_16x16x32_f16(a[mt], bihf[g * 4], acc[g * 4 + mt], 0, 0, 0);
      }
    } else {
      const h16* hlow = hring + ((size_t)(l - 1) * DEPTH + (tp & (DEPTH - 1))) * BATCH * HID;
#pragma unroll
      for (int ks = 0; ks < 4; ++ks) {
        h16x8 a[4];
#pragma unroll
        for (int mt = 0; mt < 4; ++mt)
          a[mt] = load8_dev(hlow + (size_t)(mt * 16 + nlo) * HID + kw * 128 + ks * 32 + quad * 8);
#pragma unroll
        for (int g = 0; g < 4; ++g)
#pragma unroll
          for (int mt = 0; mt < 4; ++mt)
            acc[g * 4 + mt] = __builtin_amdgcn_mfma_f32_16x16x32_f16(a[mt], bihf[g * 4 + ks], acc[g * 4 + mt], 0, 0, 0);
      }
    }
  };

  prefetch_input(0);

#pragma clang loop unroll(disable)
  for (int t = 0; t < SEQ; ++t) {
    const int slot_r = (t + DEPTH - 1) & (DEPTH - 1);
    const int slot_w = t & (DEPTH - 1);

    // ---- C: wait peers (rdy >= t) + ring backpressure (checked early, slack ~2 steps) ----
    if (tid < 64) {
      const unsigned* p = nullptr; unsigned tg = 0;
      if (tid < 32) { p = rdy_own + tid; tg = (unsigned)t; }
      else if (l < LAYERS - 1) {
        p = dn_own + (tid - 32);
        tg = (t >= DEPTH - 1) ? (unsigned)(t - (DEPTH - 1)) : 0u;
      }
      int ok = p ? ((aload(p) >= tg) ? 1 : 0) : 1;
      while (!__all(ok)) {
        __builtin_amdgcn_s_sleep(1);
        if (p) ok = (aload(p) >= tg) ? 1 : 0;
      }
    }
    __syncthreads();
    // h_low(t) consumed in prefetch (all waves past barrier): release producer
    if (tid == 0 && l > 0) astore(dn_low + slice, (unsigned)(t + 1));

    // ---- D: recurrent GEMM over this wave's K-chunk ----
    const h16* hprev = hring + ((size_t)l * DEPTH + slot_r) * BATCH * HID;
#pragma unroll
    for (int ks = 0; ks < 4; ++ks) {
      h16x8 a[4];
#pragma unroll
      for (int mt = 0; mt < 4; ++mt)
        a[mt] = load8_dev(hprev + (size_t)(mt * 16 + nlo) * HID + kw * 128 + ks * 32 + quad * 8);
#pragma unroll
      for (int g = 0; g < 4; ++g)
#pragma unroll
        for (int mt = 0; mt < 4; ++mt)
          acc[g * 4 + mt] = __builtin_amdgcn_mfma_f32_16x16x32_f16(a[mt], bhh[g * 4 + ks], acc[g * 4 + mt], 0, 0, 0);
    }

    // ---- E: partials -> LDS (m = quad*4+reg+16*mt, n = nlo; chunk-XOR swizzle) ----
#pragma unroll
    for (int g = 0; g < 4; ++g)
#pragma unroll
      for (int mt = 0; mt < 4; ++mt) {
        int idx = ((kw << 6) + (g << 4) + nlo) * 64 + ((((mt << 2) + quad) ^ (nlo & 7)) << 2);
        *(f32x4*)(pbuf + idx) = acc[g * 4 + mt];
      }
    __syncthreads();

    // ---- epilogue: reduce 4 wave-partials, LSTM cell ----
    float hv[4];
    {
      float gsum[4][4];
#pragma unroll
      for (int g = 0; g < 4; ++g)
#pragma unroll
        for (int jj = 0; jj < 4; ++jj) {
          int n = (g << 4) + ejq * 4 + jj;
          int woff = n * 64 + ((((eb >> 2) ^ (n & 7)) << 2) | (eb & 3));
          float s = pbuf[woff] + pbuf[(1 << 12) + woff] + pbuf[(2 << 12) + woff] + pbuf[(3 << 12) + woff];
          gsum[g][jj] = s + bias2[g][jj];
        }
#pragma unroll
      for (int jj = 0; jj < 4; ++jj) {
        float iv = fast_sig(gsum[0][jj]);
        float fv = fast_sig(gsum[1][jj]);
        float gg = fast_tanh(gsum[2][jj]);
        float ov = fast_sig(gsum[3][jj]);
        float cn = fv * cr[jj] + iv * gg;
        cr[jj] = cn;
        hv[jj] = ov * fast_tanh(cn);
      }
    }

    // ---- F: one coalesced 8B device-scope store per thread ----
    h16* hout = hring + ((size_t)l * DEPTH + slot_w) * BATCH * HID;
    {
      union { h16 h[4]; unsigned long long u; } pk;
#pragma unroll
      for (int jj = 0; jj < 4; ++jj) pk.h[jj] = (h16)hv[jj];
      __hip_atomic_store((unsigned long long*)(hout + (size_t)eb * HID + jbase), pk.u,
                         __ATOMIC_RELAXED, __HIP_MEMORY_SCOPE_AGENT);
      if (l == LAYERS - 1 && t == SEQ - 1) {
#pragma unroll
        for (int jj = 0; jj < 4; ++jj) h7[(size_t)eb * HID + jbase + jj] = hv[jj];
      }
    }
    __syncthreads();  // vmcnt(0) drain of all h stores before flag
    // ---- G: publish progress ----
    if (tid == 0) astore(rdy_own + slice, (unsigned)(t + 1));

    // ---- prefetch next step's input projection (hidden under peers' detect) ----
    if (t + 1 < SEQ) prefetch_input(t + 1);
  }
}

// ---------------- head ----------------
__global__ void final_kernel(const float* __restrict__ h7,
                             const float* __restrict__ Wlin,
                             const float* __restrict__ blin,
                             float* __restrict__ out) {
  int tid = threadIdx.x;
  if (tid < BATCH * 2) {
    int b = tid >> 1;
    int o = tid & 1;
    float s = 0.f;
    for (int jx = 0; jx < HID; ++jx) s += h7[(size_t)b * HID + jx] * Wlin[o * HID + jx];
    out[b * 2 + o] = s + blin[o];
  }
}

extern "C" void kernel_launch(void* const* d_in, const int* in_sizes, int n_in,
                              void* d_out, int out_size, void* d_ws, size_t ws_size,
                              hipStream_t stream) {
  (void)in_sizes; (void)n_in; (void)out_size; (void)ws_size;
  const float* x    = (const float*)d_in[0];
  const float* Wih0 = (const float*)d_in[1];
  const float* WihR = (const float*)d_in[2];
  const float* Whh  = (const float*)d_in[3];
  const float* bih  = (const float*)d_in[4];
  const float* bhh  = (const float*)d_in[5];
  const float* Wlin = (const float*)d_in[6];
  const float* blin = (const float*)d_in[7];
  float* out = (float*)d_out;

  char* ws = (char*)d_ws;
  h16* wf16       = (h16*)(ws);
  float* biasc    = (float*)(ws + BIASC_OFF);
  h16* xT         = (h16*)(ws + XT_OFF);
  h16* hring      = (h16*)(ws + HRING_OFF);
  float* h7       = (float*)(ws + H7_OFF);
  unsigned* ready = (unsigned*)(ws + READY_OFF);
  unsigned* done  = (unsigned*)(ws + DONE_OFF);

  prep_kernel<<<512, 256, 0, stream>>>(x, Wih0, WihR, Whh, bih, bhh,
                                       wf16, biasc, xT, hring, ready, done);
  lstm_persist<<<256, 256, 0, stream>>>(wf16, biasc, xT, hring, h7, ready, done);
  final_kernel<<<1, 128, 0, stream>>>(h7, Wlin, blin, out);
}

// Round 6
// 2449.808 us; speedup vs baseline: 4.1971x; 1.2572x over previous
//
#include <hip/hip_runtime.h>

#define LAYERS 8
#define SEQ 256
#define BATCH 64
#define HID 512
#define G4 2048   // 4*HID, pytorch gate order i,f,g,o
#define NSENS 64

typedef _Float16 h16;
typedef h16 h16x8 __attribute__((ext_vector_type(8)));
typedef float f32x4 __attribute__((ext_vector_type(4)));

// ---- workspace layout (bytes); end = 38,079,552 < 38,207,488 (R1-proven) ----
#define WHH_ELEMS   (LAYERS * G4 * HID)
#define WIHR_ELEMS  ((LAYERS - 1) * G4 * HID)
#define WIH0_ELEMS  (G4 * NSENS)
#define WF16_BYTES  ((size_t)(WHH_ELEMS + WIHR_ELEMS + WIH0_ELEMS) * 2)   // 31,719,424
#define BIASC_OFF   (WF16_BYTES)                                          // fp32 [L][G4]
#define XT_OFF      (BIASC_OFF + (size_t)LAYERS * G4 * 4)                 // h16 [T][B][NSENS]
#define HRING_OFF   (XT_OFF + (size_t)SEQ * BATCH * NSENS * 2)            // h16 [L][2][B][H]   intra-layer
#define HFWD_OFF    (HRING_OFF + (size_t)LAYERS * 2 * BATCH * HID * 2)    // h16 [L-1][2][B][H] cross-layer
#define H7_OFF      (HFWD_OFF + (size_t)(LAYERS - 1) * 2 * BATCH * HID * 2) // fp32 [B][H]
#define READY_OFF   (H7_OFF + (size_t)BATCH * HID * 4)                    // u32 [L][32]
#define RDYF_OFF    (READY_OFF + (size_t)LAYERS * 32 * 4)                 // u32 [L][32]
#define DONE_OFF    (RDYF_OFF + (size_t)LAYERS * 32 * 4)                  // u32 [L][32]
#define VOTE_OFF    (DONE_OFF + (size_t)LAYERS * 32 * 4)                  // u32 [L]
#define VCNT_OFF    (VOTE_OFF + (size_t)LAYERS * 4)                       // u32 [L]

__device__ __forceinline__ unsigned aload(const unsigned* p) {
  return __hip_atomic_load(p, __ATOMIC_RELAXED, __HIP_MEMORY_SCOPE_AGENT);
}
__device__ __forceinline__ void astore(unsigned* p, unsigned v) {
  __hip_atomic_store(p, v, __ATOMIC_RELAXED, __HIP_MEMORY_SCOPE_AGENT);
}
// L2-coherent (same-XCD) flag ops: bypass L1 only
__device__ __forceinline__ unsigned poll_sc0(const unsigned* p) {
  unsigned r;
  asm volatile("global_load_dword %0, %1, off sc0\n\ts_waitcnt vmcnt(0)"
               : "=&v"(r) : "v"(p) : "memory");
  return r;
}
__device__ __forceinline__ void flag_sc0(unsigned* p, unsigned v) {
  asm volatile("global_store_dword %0, %1, off sc0" :: "v"(p), "v"(v) : "memory");
}
__device__ __forceinline__ void store8_sc0(h16* p, unsigned long long v) {
  asm volatile("global_store_dwordx2 %0, %1, off sc0" :: "v"(p), "v"(v) : "memory");
}
__device__ __forceinline__ void store8_dev(h16* p, unsigned long long v) {
  asm volatile("global_store_dwordx2 %0, %1, off sc0 sc1" :: "v"(p), "v"(v) : "memory");
}
// 8 x 16B fragment loads (4 rows x 2 K-subchunks via +64B imm), one waitcnt.
// ALL outputs early-clobber: results return async and must not alias the
// pointer pairs still being consumed by later loads in the block.
template <bool SC1>
__device__ __forceinline__ void load8x16(const h16* p0, const h16* p1, const h16* p2, const h16* p3,
                                         h16x8& f0, h16x8& f1, h16x8& f2, h16x8& f3,
                                         h16x8& f4, h16x8& f5, h16x8& f6, h16x8& f7) {
  if (SC1)
    asm volatile(
      "global_load_dwordx4 %0, %8, off sc0 sc1\n\t"
      "global_load_dwordx4 %1, %9, off sc0 sc1\n\t"
      "global_load_dwordx4 %2, %10, off sc0 sc1\n\t"
      "global_load_dwordx4 %3, %11, off sc0 sc1\n\t"
      "global_load_dwordx4 %4, %8, off offset:64 sc0 sc1\n\t"
      "global_load_dwordx4 %5, %9, off offset:64 sc0 sc1\n\t"
      "global_load_dwordx4 %6, %10, off offset:64 sc0 sc1\n\t"
      "global_load_dwordx4 %7, %11, off offset:64 sc0 sc1\n\t"
      "s_waitcnt vmcnt(0)"
      : "=&v"(f0), "=&v"(f1), "=&v"(f2), "=&v"(f3), "=&v"(f4), "=&v"(f5), "=&v"(f6), "=&v"(f7)
      : "v"(p0), "v"(p1), "v"(p2), "v"(p3) : "memory");
  else
    asm volatile(
      "global_load_dwordx4 %0, %8, off sc0\n\t"
      "global_load_dwordx4 %1, %9, off sc0\n\t"
      "global_load_dwordx4 %2, %10, off sc0\n\t"
      "global_load_dwordx4 %3, %11, off sc0\n\t"
      "global_load_dwordx4 %4, %8, off offset:64 sc0\n\t"
      "global_load_dwordx4 %5, %9, off offset:64 sc0\n\t"
      "global_load_dwordx4 %6, %10, off offset:64 sc0\n\t"
      "global_load_dwordx4 %7, %11, off offset:64 sc0\n\t"
      "s_waitcnt vmcnt(0)"
      : "=&v"(f0), "=&v"(f1), "=&v"(f2), "=&v"(f3), "=&v"(f4), "=&v"(f5), "=&v"(f6), "=&v"(f7)
      : "v"(p0), "v"(p1), "v"(p2), "v"(p3) : "memory");
}
__device__ __forceinline__ float fast_sig(float x) { return 1.f / (1.f + __expf(-x)); }
__device__ __forceinline__ float fast_tanh(float x) {
  x = fminf(fmaxf(x, -10.f), 10.f);
  float e2 = __expf(2.f * x);
  return (e2 - 1.f) / (e2 + 1.f);
}

// ---------------- prep ----------------
__global__ void prep_kernel(const float* __restrict__ x,
                            const float* __restrict__ Wih0,
                            const float* __restrict__ WihR,
                            const float* __restrict__ Whh,
                            const float* __restrict__ bih,
                            const float* __restrict__ bhh,
                            h16* __restrict__ wf16,
                            float* __restrict__ biasc,
                            h16* __restrict__ xT,
                            h16* __restrict__ hring,
                            h16* __restrict__ hfwd,
                            unsigned* __restrict__ flags /* ready..vcnt contiguous */) {
  const int tid = blockIdx.x * blockDim.x + threadIdx.x;
  const int nt = gridDim.x * blockDim.x;
  for (int i = tid; i < WHH_ELEMS; i += nt) wf16[i] = (h16)Whh[i];
  for (int i = tid; i < WIHR_ELEMS; i += nt) wf16[WHH_ELEMS + i] = (h16)WihR[i];
  for (int i = tid; i < WIH0_ELEMS; i += nt) wf16[WHH_ELEMS + WIHR_ELEMS + i] = (h16)Wih0[i];
  for (int i = tid; i < LAYERS * G4; i += nt) biasc[i] = bih[i] + bhh[i];
  for (int i = tid; i < SEQ * BATCH * NSENS; i += nt) {
    int t = i / (BATCH * NSENS);
    int r = i - t * (BATCH * NSENS);
    int b = r / NSENS;
    int s2 = r - b * NSENS;
    xT[i] = (h16)x[(b * SEQ + t) * NSENS + s2];
  }
  for (int i = tid; i < LAYERS * 2 * BATCH * HID; i += nt) hring[i] = (h16)0.f;
  for (int i = tid; i < (LAYERS - 1) * 2 * BATCH * HID; i += nt) hfwd[i] = (h16)0.f;
  // ready[256] + rdyf[256] + done[256] + vote[8] + vcnt[8] = 784 words
  for (int i = tid; i < LAYERS * 32 * 3 + LAYERS * 2; i += nt) flags[i] = 0u;
}

// ---------------- persistent dataflow LSTM ----------------
// layer = blockIdx & 7, slice = blockIdx >> 3. wave kw = K-chunk of 128.
// Weights in VGPRs. Input GEMM software-pipelined one step ahead.
// Intra-layer exchange (hring/ready): sc0/L2-local when the layer's 32 WGs
// verify (runtime vote on HW_REG_XCC_ID) they share one XCD; else agent scope.
// Cross-layer exchange (hfwd/rdyf/done): always agent scope (LLC).
__global__ __launch_bounds__(256, 2) void lstm_persist(
    const h16* __restrict__ wf16, const float* __restrict__ biasc,
    const h16* __restrict__ xT, h16* __restrict__ hring, h16* __restrict__ hfwd,
    float* __restrict__ h7, unsigned* __restrict__ ready,
    unsigned* __restrict__ rdyf, unsigned* __restrict__ done,
    unsigned* __restrict__ vote, unsigned* __restrict__ vcnt) {
  const int l = blockIdx.x & 7;
  const int slice = blockIdx.x >> 3;
  const int tid = threadIdx.x;
  const int kw = tid >> 6;
  const int lane = tid & 63;
  const int nlo = lane & 15;
  const int quad = lane >> 4;

  __shared__ float pbuf[4 * 64 * 64];
  __shared__ int s_fast;

  // ---- XCD vote: fast path only if all 32 WGs of this layer share one XCD ----
  if (tid == 0) {
    unsigned xcc;
    asm volatile("s_getreg_b32 %0, hwreg(HW_REG_XCC_ID)" : "=s"(xcc));
    atomicOr(vote + l, 1u << (xcc & 31));
    __threadfence();
    atomicAdd(vcnt + l, 1u);
    while (aload(vcnt + l) < 32u) __builtin_amdgcn_s_sleep(2);
    s_fast = (__popc(aload(vote + l)) == 1) ? 1 : 0;
  }
  __syncthreads();
  const bool fast = (s_fast != 0);

  const h16* Whh = wf16 + (size_t)l * G4 * HID;
  const h16* Wih = (l == 0) ? (wf16 + WHH_ELEMS + WIHR_ELEMS)
                            : (wf16 + WHH_ELEMS + (size_t)(l - 1) * G4 * HID);

  // ---- persistent weight fragments ----
  h16x8 bhh[16];   // [g*4+ks]
  h16x8 bihf[16];
  {
    const int row_in_gate = slice * 16 + nlo;
#pragma unroll
    for (int g = 0; g < 4; ++g) {
      const size_t rhh = (size_t)(g * HID + row_in_gate) * HID + kw * 128 + quad * 8;
#pragma unroll
      for (int ks = 0; ks < 4; ++ks)
        bhh[g * 4 + ks] = *(const h16x8*)(Whh + rhh + ks * 32);
      if (l == 0) {
        if (kw < 2)
          bihf[g * 4] = *(const h16x8*)(Wih + (size_t)(g * HID + row_in_gate) * NSENS + kw * 32 + quad * 8);
      } else {
        const size_t rih = (size_t)(g * HID + row_in_gate) * HID + kw * 128 + quad * 8;
#pragma unroll
        for (int ks = 0; ks < 4; ++ks)
          bihf[g * 4 + ks] = *(const h16x8*)(Wih + rih + ks * 32);
      }
    }
  }

  // ---- epilogue mapping: thread = (batch, j-quad): one 8B store per buffer ----
  const int eb = tid >> 2;
  const int ejq = tid & 3;
  const int jbase = slice * 16 + ejq * 4;
  float bias2[4][4];
#pragma unroll
  for (int g = 0; g < 4; ++g)
#pragma unroll
    for (int jj = 0; jj < 4; ++jj)
      bias2[g][jj] = biasc[l * G4 + g * HID + jbase + jj];
  float cr[4] = {0.f, 0.f, 0.f, 0.f};

  unsigned* rdy_own = ready + l * 32;
  unsigned* rdyf_own = rdyf + l * 32;
  unsigned* rdyf_low = rdyf + (l > 0 ? (l - 1) * 32 : 0);
  unsigned* dn_own = done + l * 32;
  unsigned* dn_low = done + (l > 0 ? (l - 1) * 32 : 0);

  f32x4 acc[16];
  const int kbase = kw * 128;

  // GEMM over one 128-wide K chunk from a [B][H] h buffer
  auto gemm_chunk = [&](const h16* hbase, const h16x8* bw, bool sc1) {
#pragma unroll
    for (int kp = 0; kp < 2; ++kp) {
      const h16* q = hbase + kbase + kp * 64 + quad * 8;
      h16x8 f0, f1, f2, f3, f4, f5, f6, f7;
      if (sc1)
        load8x16<true>(q + (size_t)(0 * 16 + nlo) * HID, q + (size_t)(1 * 16 + nlo) * HID,
                       q + (size_t)(2 * 16 + nlo) * HID, q + (size_t)(3 * 16 + nlo) * HID,
                       f0, f1, f2, f3, f4, f5, f6, f7);
      else
        load8x16<false>(q + (size_t)(0 * 16 + nlo) * HID, q + (size_t)(1 * 16 + nlo) * HID,
                        q + (size_t)(2 * 16 + nlo) * HID, q + (size_t)(3 * 16 + nlo) * HID,
                        f0, f1, f2, f3, f4, f5, f6, f7);
      const int ks0 = kp * 2;
#pragma unroll
      for (int g = 0; g < 4; ++g) {
        acc[g * 4 + 0] = __builtin_amdgcn_mfma_f32_16x16x32_f16(f0, bw[g * 4 + ks0], acc[g * 4 + 0], 0, 0, 0);
        acc[g * 4 + 1] = __builtin_amdgcn_mfma_f32_16x16x32_f16(f1, bw[g * 4 + ks0], acc[g * 4 + 1], 0, 0, 0);
        acc[g * 4 + 2] = __builtin_amdgcn_mfma_f32_16x16x32_f16(f2, bw[g * 4 + ks0], acc[g * 4 + 2], 0, 0, 0);
        acc[g * 4 + 3] = __builtin_amdgcn_mfma_f32_16x16x32_f16(f3, bw[g * 4 + ks0], acc[g * 4 + 3], 0, 0, 0);
      }
#pragma unroll
      for (int g = 0; g < 4; ++g) {
        acc[g * 4 + 0] = __builtin_amdgcn_mfma_f32_16x16x32_f16(f4, bw[g * 4 + ks0 + 1], acc[g * 4 + 0], 0, 0, 0);
        acc[g * 4 + 1] = __builtin_amdgcn_mfma_f32_16x16x32_f16(f5, bw[g * 4 + ks0 + 1], acc[g * 4 + 1], 0, 0, 0);
        acc[g * 4 + 2] = __builtin_amdgcn_mfma_f32_16x16x32_f16(f6, bw[g * 4 + ks0 + 1], acc[g * 4 + 2], 0, 0, 0);
        acc[g * 4 + 3] = __builtin_amdgcn_mfma_f32_16x16x32_f16(f7, bw[g * 4 + ks0 + 1], acc[g * 4 + 3], 0, 0, 0);
      }
    }
  };

  // ---- prefetch input contribution for timestep tp into acc ----
  auto prefetch_input = [&](int tp) {
    if (l > 0) {
      if (tid < 32) {
        const unsigned* p = rdyf_low + tid;
        while (aload(p) < (unsigned)(tp + 1)) __builtin_amdgcn_s_sleep(1);
      }
      __syncthreads();
    }
#pragma unroll
    for (int i = 0; i < 16; ++i) acc[i] = (f32x4){0.f, 0.f, 0.f, 0.f};
    if (l == 0) {
      if (kw < 2) {
        const h16* xrow = xT + (size_t)tp * BATCH * NSENS;
        h16x8 a[4];
#pragma unroll
        for (int mt = 0; mt < 4; ++mt)
          a[mt] = *(const h16x8*)(xrow + (size_t)(mt * 16 + nlo) * NSENS + kw * 32 + quad * 8);
#pragma unroll
        for (int g = 0; g < 4; ++g)
#pragma unroll
          for (int mt = 0; mt < 4; ++mt)
            acc[g * 4 + mt] = __builtin_amdgcn_mfma_f32_16x16x32_f16(a[mt], bihf[g * 4], acc[g * 4 + mt], 0, 0, 0);
      }
    } else {
      const h16* hlow = hfwd + ((size_t)(l - 1) * 2 + (tp & 1)) * BATCH * HID;
      gemm_chunk(hlow, bihf, true);
    }
  };

  prefetch_input(0);

#pragma clang loop unroll(disable)
  for (int t = 0; t < SEQ; ++t) {
    // ---- C: wait peers (finished t-1) + forward-ring backpressure (dn >= t-1) ----
    if (tid < 64) {
      const unsigned* p = nullptr; unsigned tg = 0; bool sc0poll = false;
      if (tid < 32) { p = rdy_own + tid; tg = (unsigned)t; sc0poll = fast; }
      else if (l < LAYERS - 1) {
        p = dn_own + (tid - 32);
        tg = (t >= 1) ? (unsigned)(t - 1) : 0u;
      }
      if (p) {
        if (sc0poll) { while (poll_sc0(p) < tg) __builtin_amdgcn_s_sleep(1); }
        else         { while (aload(p)   < tg) __builtin_amdgcn_s_sleep(1); }
      }
    }
    __syncthreads();
    // h_low(t) consumed in prefetch: release producer's forward slot
    if (tid == 0 && l > 0) astore(dn_low + slice, (unsigned)(t + 1));

    // ---- recurrent GEMM: h_prev from hring (L2-local when fast) ----
    const h16* hprev = hring + ((size_t)l * 2 + ((t + 1) & 1)) * BATCH * HID;
    gemm_chunk(hprev, bhh, !fast);

    // ---- partials -> LDS (m = quad*4+reg+16*mt, n = nlo; chunk-XOR swizzle) ----
#pragma unroll
    for (int g = 0; g < 4; ++g)
#pragma unroll
      for (int mt = 0; mt < 4; ++mt) {
        int idx = ((kw << 6) + (g << 4) + nlo) * 64 + ((((mt << 2) + quad) ^ (nlo & 7)) << 2);
        *(f32x4*)(pbuf + idx) = acc[g * 4 + mt];
      }
    __syncthreads();

    // ---- epilogue: reduce 4 wave-partials, LSTM cell ----
    float hv[4];
    {
      float gsum[4][4];
#pragma unroll
      for (int g = 0; g < 4; ++g)
#pragma unroll
        for (int jj = 0; jj < 4; ++jj) {
          int n = (g << 4) + ejq * 4 + jj;
          int woff = n * 64 + ((((eb >> 2) ^ (n & 7)) << 2) | (eb & 3));
          float s = pbuf[woff] + pbuf[(1 << 12) + woff] + pbuf[(2 << 12) + woff] + pbuf[(3 << 12) + woff];
          gsum[g][jj] = s + bias2[g][jj];
        }
#pragma unroll
      for (int jj = 0; jj < 4; ++jj) {
        float iv = fast_sig(gsum[0][jj]);
        float fv = fast_sig(gsum[1][jj]);
        float gg = fast_tanh(gsum[2][jj]);
        float ov = fast_sig(gsum[3][jj]);
        float cn = fv * cr[jj] + iv * gg;
        cr[jj] = cn;
        hv[jj] = ov * fast_tanh(cn);
      }
    }

    // ---- store h: hring (peers) + hfwd (next layer), 8B coalesced each ----
    {
      union { h16 h[4]; unsigned long long u; } pk;
#pragma unroll
      for (int jj = 0; jj < 4; ++jj) pk.h[jj] = (h16)hv[jj];
      h16* pr = hring + ((size_t)l * 2 + (t & 1)) * BATCH * HID + (size_t)eb * HID + jbase;
      if (fast) store8_sc0(pr, pk.u); else store8_dev(pr, pk.u);
      if (l < LAYERS - 1) {
        h16* pf = hfwd + ((size_t)l * 2 + (t & 1)) * BATCH * HID + (size_t)eb * HID + jbase;
        store8_dev(pf, pk.u);
      }
      if (l == LAYERS - 1 && t == SEQ - 1) {
#pragma unroll
        for (int jj = 0; jj < 4; ++jj) h7[(size_t)eb * HID + jbase + jj] = hv[jj];
      }
    }
    asm volatile("s_waitcnt vmcnt(0)" ::: "memory");  // all h stores at coherence point
    __syncthreads();
    if (tid == 0) {
      if (fast) flag_sc0(rdy_own + slice, (unsigned)(t + 1));
      else      astore(rdy_own + slice, (unsigned)(t + 1));
      if (l < LAYERS - 1) astore(rdyf_own + slice, (unsigned)(t + 1));
    }

    // ---- prefetch next step's input projection ----
    if (t + 1 < SEQ) prefetch_input(t + 1);
  }
}

// ---------------- head ----------------
__global__ void final_kernel(const float* __restrict__ h7,
                             const float* __restrict__ Wlin,
                             const float* __restrict__ blin,
                             float* __restrict__ out) {
  int tid = threadIdx.x;
  if (tid < BATCH * 2) {
    int b = tid >> 1;
    int o = tid & 1;
    float s = 0.f;
    for (int jx = 0; jx < HID; ++jx) s += h7[(size_t)b * HID + jx] * Wlin[o * HID + jx];
    out[b * 2 + o] = s + blin[o];
  }
}

extern "C" void kernel_launch(void* const* d_in, const int* in_sizes, int n_in,
                              void* d_out, int out_size, void* d_ws, size_t ws_size,
                              hipStream_t stream) {
  (void)in_sizes; (void)n_in; (void)out_size; (void)ws_size;
  const float* x    = (const float*)d_in[0];
  const float* Wih0 = (const float*)d_in[1];
  const float* WihR = (const float*)d_in[2];
  const float* Whh  = (const float*)d_in[3];
  const float* bih  = (const float*)d_in[4];
  const float* bhh  = (const float*)d_in[5];
  const float* Wlin = (const float*)d_in[6];
  const float* blin = (const float*)d_in[7];
  float* out = (float*)d_out;

  char* ws = (char*)d_ws;
  h16* wf16       = (h16*)(ws);
  float* biasc    = (float*)(ws + BIASC_OFF);
  h16* xT         = (h16*)(ws + XT_OFF);
  h16* hring      = (h16*)(ws + HRING_OFF);
  h16* hfwd       = (h16*)(ws + HFWD_OFF);
  float* h7       = (float*)(ws + H7_OFF);
  unsigned* ready = (unsigned*)(ws + READY_OFF);
  unsigned* rdyfp = (unsigned*)(ws + RDYF_OFF);
  unsigned* done  = (unsigned*)(ws + DONE_OFF);
  unsigned* vote  = (unsigned*)(ws + VOTE_OFF);
  unsigned* vcnt  = (unsigned*)(ws + VCNT_OFF);

  prep_kernel<<<512, 256, 0, stream>>>(x, Wih0, WihR, Whh, bih, bhh,
                                       wf16, biasc, xT, hring, hfwd, ready);
  lstm_persist<<<256, 256, 0, stream>>>(wf16, biasc, xT, hring, hfwd, h7,
                                        ready, rdyfp, done, vote, vcnt);
  final_kernel<<<1, 128, 0, stream>>>(h7, Wlin, blin, out);
}